// Round 10
// baseline (17710.246 us; speedup 1.0000x reference)
//
#include <hip/hip_runtime.h>

#define BB 256
#define HH 1024
#define EE 256
#define VV 28
#define ZZ 1024
#define TT 512
#define G3 3072
#define NTHR 256
#define TOKBASE (BB * TT * VV)

#define BM 64
#define BN 64
#define KT 32

// k_mm tile: 128(M) x 48(N), 2 m-tiles x 64 bn-tiles x 3 mats = 384 blocks
#define MMN 48
#define NBN 64                      // 3072 / 48

typedef float f4 __attribute__((ext_vector_type(4)));
typedef float f32x4 __attribute__((ext_vector_type(4)));
typedef _Float16 f16x8 __attribute__((ext_vector_type(8)));   // 8 fp16 = 4 VGPR
typedef unsigned short u16x4 __attribute__((ext_vector_type(4)));
typedef unsigned short u16x8 __attribute__((ext_vector_type(8)));

#define RES_SCALE 512.0f
#define INV_RES (1.0f / 512.0f)

// ---- persistent state (fully rewritten every call; deterministic) ----
__device__ __align__(16) float g_h0[2][BB][HH];
__device__ __align__(16) float g_h1[2][BB][HH];
__device__ __align__(16) float g_gh0b[BB][G3];
__device__ __align__(16) float g_gh1b[BB][G3];
__device__ __align__(16) float g_gi1[BB][G3];
__device__ __align__(16) float g_P0[VV][G3];
// Tiled (staging-order) fp16 2-split operands. ks = k-block of 32, s = split,
// kk = 8-wide k chunk. Split 1 = fp16(x); split 2 = fp16((x - x1)*512).
__device__ __align__(16) unsigned short g_h0t[32][2][4][BB][8];   // 1 MB
__device__ __align__(16) unsigned short g_h1t[32][2][4][BB][8];   // 1 MB
// mat 0 = w_ih1, 1 = w_hh0, 2 = w_hh1; bn = 48-col tile
__device__ __align__(16) unsigned short g_wt[3][NBN][32][2][4][MMN][8];  // 37.7 MB

// ---- threefry2x32, JAX-exact (20 rounds) ----
__device__ __forceinline__ uint2 tf2x32(unsigned k0, unsigned k1,
                                        unsigned x0, unsigned x1) {
  unsigned ks2 = k0 ^ k1 ^ 0x1BD11BDAu;
  unsigned ksl[3] = {k0, k1, ks2};
  x0 += k0; x1 += k1;
#pragma unroll
  for (int g = 0; g < 5; ++g) {
    const int r0 = (g & 1) ? 17 : 13;
    const int r1 = (g & 1) ? 29 : 15;
    const int r2 = (g & 1) ? 16 : 26;
    const int r3 = (g & 1) ? 24 : 6;
    x0 += x1; x1 = (x1 << r0) | (x1 >> (32 - r0)); x1 ^= x0;
    x0 += x1; x1 = (x1 << r1) | (x1 >> (32 - r1)); x1 ^= x0;
    x0 += x1; x1 = (x1 << r2) | (x1 >> (32 - r2)); x1 ^= x0;
    x0 += x1; x1 = (x1 << r3) | (x1 >> (32 - r3)); x1 ^= x0;
    x0 += ksl[(g + 1) % 3];
    x1 += ksl[(g + 2) % 3] + (unsigned)(g + 1);
  }
  return make_uint2(x0, x1);
}

__device__ __forceinline__ float sigf(float x) {
  return 1.0f / (1.0f + expf(-x));
}

__device__ __forceinline__ float gru_h(float i_r, float h_r, float i_z, float h_z,
                                       float i_n, float h_n, float hprev) {
  float r  = sigf(i_r + h_r);
  float zg = sigf(i_z + h_z);
  float n  = tanhf(i_n + r * h_n);
  return (1.0f - zg) * n + zg * hprev;
}

// fp16 2-way split: x ~= x1 + x2/512, residual stored scaled to dodge subnormals
__device__ __forceinline__ void split2(float x, unsigned short& a,
                                       unsigned short& b) {
  _Float16 h1 = (_Float16)x;
  _Float16 h2 = (_Float16)((x - (float)h1) * RES_SCALE);
  a = __builtin_bit_cast(unsigned short, h1);
  b = __builtin_bit_cast(unsigned short, h2);
}

// async global->LDS, 16B per lane
__device__ __forceinline__ void gload16(unsigned short* l, const unsigned short* g) {
  __builtin_amdgcn_global_load_lds(
      (const __attribute__((address_space(1))) unsigned int*)(g),
      (__attribute__((address_space(3))) unsigned int*)(l), 16, 0, 0);
}

// ---------------- fp32 tiled GEMM (setup only) ----------------
__device__ __forceinline__ void gemm_unit(
    const float* __restrict__ At, int lda, int rows_valid,
    const float* __restrict__ Wt, int ldw,
    const float* __restrict__ bias,
    float* __restrict__ Ct, int ldc,
    int K, int mode,
    float (&As)[BM][KT + 4], float (&Ws)[KT][BN + 4]) {
  const int tid = threadIdx.x;
  const int tx = tid & 15, ty = tid >> 4;
  f4 acc0 = {0.f, 0.f, 0.f, 0.f};
  f4 acc1 = {0.f, 0.f, 0.f, 0.f};
  f4 acc2 = {0.f, 0.f, 0.f, 0.f};
  f4 acc3 = {0.f, 0.f, 0.f, 0.f};

  for (int kb = 0; kb < K; kb += KT) {
#pragma unroll
    for (int l = 0; l < 2; ++l) {
      int f = tid + l * NTHR;
      int r = f >> 3, kq = (f & 7) << 2;
      f4 v = {0.f, 0.f, 0.f, 0.f};
      if (r < rows_valid) v = *(const f4*)(At + r * lda + kb + kq);
      *(f4*)&As[r][kq] = v;
    }
#pragma unroll
    for (int l = 0; l < 2; ++l) {
      int f = tid + l * NTHR;
      int nr = f >> 3, kq = (f & 7) << 2;
      f4 v = *(const f4*)(Wt + nr * ldw + kb + kq);
      Ws[kq + 0][nr] = v[0];
      Ws[kq + 1][nr] = v[1];
      Ws[kq + 2][nr] = v[2];
      Ws[kq + 3][nr] = v[3];
    }
    __syncthreads();
#pragma unroll
    for (int kk = 0; kk < KT; kk += 4) {
      f4 a0 = *(const f4*)&As[(ty << 2) + 0][kk];
      f4 a1 = *(const f4*)&As[(ty << 2) + 1][kk];
      f4 a2 = *(const f4*)&As[(ty << 2) + 2][kk];
      f4 a3 = *(const f4*)&As[(ty << 2) + 3][kk];
      f4 b0 = *(const f4*)&Ws[kk + 0][tx << 2];
      f4 b1 = *(const f4*)&Ws[kk + 1][tx << 2];
      f4 b2 = *(const f4*)&Ws[kk + 2][tx << 2];
      f4 b3 = *(const f4*)&Ws[kk + 3][tx << 2];
      acc0 += b0 * a0[0]; acc0 += b1 * a0[1]; acc0 += b2 * a0[2]; acc0 += b3 * a0[3];
      acc1 += b0 * a1[0]; acc1 += b1 * a1[1]; acc1 += b2 * a1[2]; acc1 += b3 * a1[3];
      acc2 += b0 * a2[0]; acc2 += b1 * a2[1]; acc2 += b2 * a2[2]; acc2 += b3 * a2[3];
      acc3 += b0 * a3[0]; acc3 += b1 * a3[1]; acc3 += b2 * a3[2]; acc3 += b3 * a3[3];
    }
    __syncthreads();
  }

  f4 accs[4] = {acc0, acc1, acc2, acc3};
#pragma unroll
  for (int i = 0; i < 4; ++i) {
    int r = (ty << 2) + i;
    if (r < rows_valid) {
#pragma unroll
      for (int j = 0; j < 4; ++j) {
        int c = (tx << 2) + j;
        float v = accs[i][j] + bias[c];
        if (mode == 1) v = tanhf(v);
        Ct[r * ldc + c] = v;
      }
    }
  }
}

// ------------- MFMA tile 128(M) x 48(N), K=1024, fp16 2-split/3-product -------------
// 4 waves: wave wr owns rows [wr*32,+32) x 48 cols = 2 m-frags x 3 n-frags.
// A: global -> registers directly (zero intra-block reuse, skip LDS; double-
// buffered named reg sets, manual 2x-unrolled ks loop). W: LDS (4x wave reuse),
// double-buffered via global_load_lds; 6 KB/buffer.
#define W_CH (2 * 4 * MMN)          // 384 chunks of 16B per ks
#define WBUF (W_CH * 8)             // ushorts per buffer
#define A_KS_STRIDE (2 * 4 * BB * 8)  // ushorts per ks in g_h?t

__device__ __forceinline__ void mm_tile(
    const unsigned short* __restrict__ At,  // g_h0t / g_h1t base
    const unsigned short* __restrict__ Wt,  // &g_wt[mat][bn][0][0][0][0][0]
    const float* __restrict__ bias,
    float* __restrict__ C,                  // [BB][G3]
    int m0, int n0, unsigned short* lds) {
  const int tid = threadIdx.x;
  const int wr = tid >> 6, lane = tid & 63;
  const int lr = lane & 15, lk8 = lane >> 4;   // k8 slot 0..3

  f32x4 acc1[2][3] = {};
  f32x4 accR[2][3] = {};

  // per-lane A base: row = m0 + wr*32 + mi*16 + lr ; chunk col = lk8
  const unsigned short* abase = At + ((size_t)lk8 * BB + m0 + wr * 32 + lr) * 8;

  auto stageW = [&](int buf, int ks) {
    unsigned short* lW = lds + buf * WBUF;
    const unsigned short* wbase = Wt + (size_t)ks * WBUF;
    gload16(lW + tid * 8, wbase + (size_t)tid * 8);
    if (tid < W_CH - NTHR) {
      int j = NTHR + tid;
      gload16(lW + j * 8, wbase + (size_t)j * 8);
    }
  };

  auto loadA = [&](int ks, f16x8 (&a)[2][2]) {
#pragma unroll
    for (int mi = 0; mi < 2; ++mi)
#pragma unroll
      for (int s = 0; s < 2; ++s)
        a[mi][s] = *(const f16x8*)(abase + (size_t)ks * A_KS_STRIDE +
                                   ((size_t)s * 4 * BB + mi * 16) * 8);
  };

  auto compute = [&](int buf, f16x8 (&a)[2][2]) {
    const unsigned short* lW = lds + buf * WBUF;
    f16x8 b[3][2];
#pragma unroll
    for (int ni = 0; ni < 3; ++ni)
#pragma unroll
      for (int s = 0; s < 2; ++s)
        b[ni][s] = *(const f16x8*)(lW + (((s << 2) | lk8) * MMN + ni * 16 + lr) * 8);
#pragma unroll
    for (int mi = 0; mi < 2; ++mi)
#pragma unroll
      for (int ni = 0; ni < 3; ++ni) {
        acc1[mi][ni] = __builtin_amdgcn_mfma_f32_16x16x32_f16(a[mi][0], b[ni][0], acc1[mi][ni], 0, 0, 0);
        accR[mi][ni] = __builtin_amdgcn_mfma_f32_16x16x32_f16(a[mi][0], b[ni][1], accR[mi][ni], 0, 0, 0);
        accR[mi][ni] = __builtin_amdgcn_mfma_f32_16x16x32_f16(a[mi][1], b[ni][0], accR[mi][ni], 0, 0, 0);
      }
  };

  f16x8 aA[2][2], aB[2][2];
  stageW(0, 0);
  loadA(0, aA);
  // 16 double-iterations over 32 ks blocks; named reg sets avoid runtime idx.
  for (int kp = 0; kp < 16; ++kp) {
    __syncthreads();                    // W buf0 staged, aA loaded (vmcnt drain)
    stageW(1, 2 * kp + 1);
    loadA(2 * kp + 1, aB);
    compute(0, aA);
    __syncthreads();                    // W buf1 staged, aB loaded
    if (kp < 15) {
      stageW(0, 2 * kp + 2);
      loadA(2 * kp + 2, aA);
    }
    compute(1, aB);
  }

  // store: D layout col=lane&15, row=(lane>>4)*4+reg
#pragma unroll
  for (int mi = 0; mi < 2; ++mi) {
    int rowb = m0 + wr * 32 + mi * 16 + ((lane >> 4) << 2);
#pragma unroll
    for (int ni = 0; ni < 3; ++ni) {
      int col = n0 + ni * 16 + lr;
      float bv = bias[col];
#pragma unroll
      for (int r = 0; r < 4; ++r)
        C[(size_t)(rowb + r) * G3 + col] = acc1[mi][ni][r] + accR[mi][ni][r] * INV_RES + bv;
    }
  }
}

// write one row's 4 consecutive k of both splits into a tiled h array
__device__ __forceinline__ void write_ht(unsigned short (*ht)[2][4][BB][8],
                                         int row, int k0,
                                         u16x4 o1, u16x4 o2) {
  const int ks = k0 >> 5, kk = (k0 >> 3) & 3, e0 = k0 & 7;
  *(u16x4*)&ht[ks][0][kk][row][e0] = o1;
  *(u16x4*)&ht[ks][1][kk][row][e0] = o2;
}

// ---------------- setup kernels ----------------
__global__ __launch_bounds__(NTHR) void k_setup1(
    const float* __restrict__ z, const float* __restrict__ w_zh,
    const float* __restrict__ b_zh, const float* __restrict__ emb,
    const float* __restrict__ w_ih0, const float* __restrict__ b_ih0) {
  __shared__ __align__(16) float As[BM][KT + 4];
  __shared__ __align__(16) float Ws[KT][BN + 4];
  const int bid = blockIdx.x;
  if (bid < 128) {
    int m0 = (bid >> 5) * BM;
    int n0 = (bid & 31) * BN;
    float* Cb;
    int col;
    if (n0 < HH) { Cb = &g_h0[1][0][0]; col = n0; }
    else         { Cb = &g_h1[1][0][0]; col = n0 - HH; }
    gemm_unit(z + m0 * ZZ, ZZ, BM, w_zh + n0 * ZZ, ZZ, b_zh + n0,
              Cb + m0 * HH + col, HH, ZZ, 1, As, Ws);
  } else {
    int n0 = (bid - 128) * BN;
    gemm_unit(emb, EE, VV, w_ih0 + n0 * EE, EE, b_ih0 + n0,
              &g_P0[0][0] + n0, G3, EE, 0, As, Ws);
  }
}

// split + tile the 3 recurrent weight matrices -> g_wt (48-col tiles).
__global__ __launch_bounds__(NTHR) void k_splitw(
    const float* __restrict__ w_ih1, const float* __restrict__ w_hh0,
    const float* __restrict__ w_hh1) {
  unsigned u = blockIdx.x * NTHR + threadIdx.x;   // < 1,179,648
  int row = u % MMN;
  unsigned v = u / MMN;
  int kk = v & 3, ks = (v >> 2) & 31;
  unsigned rem = v >> 7;                           // mat*NBN + bn
  int mat = rem / NBN, bn = rem % NBN;
  const float* src = (mat == 0) ? w_ih1 : (mat == 1) ? w_hh0 : w_hh1;
  const float* p = src + (size_t)(bn * MMN + row) * HH + ks * 32 + kk * 8;
  f4 v0 = *(const f4*)p;
  f4 v1 = *(const f4*)(p + 4);
  u16x8 o1, o2;
#pragma unroll
  for (int c = 0; c < 8; ++c) {
    float x = (c < 4) ? v0[c] : v1[c - 4];
    unsigned short a, b;
    split2(x, a, b);
    o1[c] = a; o2[c] = b;
  }
  *(u16x8*)&g_wt[mat][bn][ks][0][kk][row][0] = o1;
  *(u16x8*)&g_wt[mat][bn][ks][1][kk][row][0] = o2;
}

// split h0init/h1init into tiled g_h0t/g_h1t. One thread per (mat,row,kquad).
__global__ __launch_bounds__(NTHR) void k_splith() {
  unsigned e = blockIdx.x * NTHR + threadIdx.x;   // < 131072
  int mat = e >> 16, r = (e >> 8) & 255, k0 = (e & 255) << 2;
  const float* src = (mat == 0) ? &g_h0[1][0][0] : &g_h1[1][0][0];
  f4 v = *(const f4*)(src + (size_t)r * HH + k0);
  u16x4 o1, o2;
#pragma unroll
  for (int c = 0; c < 4; ++c) {
    unsigned short a, b;
    split2(v[c], a, b);
    o1[c] = a; o2[c] = b;
  }
  write_ht((mat == 0) ? g_h0t : g_h1t, r, k0, o1, o2);
}

// gh0(-1) = h0init @ w_hh0^T + b_hh0 : 2 mt x 64 bn (mat 1 only)
__global__ __launch_bounds__(NTHR, 3) void k_mm_init(const float* __restrict__ b_hh0) {
  __shared__ __align__(16) unsigned short lds[2 * WBUF];
  int mt = blockIdx.x >> 6, bn = blockIdx.x & 63;
  mm_tile(&g_h0t[0][0][0][0][0], &g_wt[1][bn][0][0][0][0][0], b_hh0,
          &g_gh0b[0][0], mt * 128, bn * MMN, lds);
}

// gate0 for t=0 (token = SOS = 1)
__global__ __launch_bounds__(NTHR) void k_gate0_init() {
  const int b = blockIdx.x, tid = threadIdx.x, j = tid << 2;
  const float* __restrict__ gi = g_P0[1];
  const float* __restrict__ gh = g_gh0b[b];
  f4 ir = *(const f4*)&gi[j];
  f4 iz = *(const f4*)&gi[j + HH];
  f4 in_ = *(const f4*)&gi[j + 2 * HH];
  f4 hr = *(const f4*)&gh[j];
  f4 hz = *(const f4*)&gh[j + HH];
  f4 hn = *(const f4*)&gh[j + 2 * HH];
  f4 hp = *(const f4*)&g_h0[1][b][j];
  f4 ho;
  u16x4 o1, o2;
#pragma unroll
  for (int c = 0; c < 4; ++c) {
    ho[c] = gru_h(ir[c], hr[c], iz[c], hz[c], in_[c], hn[c], hp[c]);
    unsigned short a, bb2;
    split2(ho[c], a, bb2);
    o1[c] = a; o2[c] = bb2;
  }
  *(f4*)&g_h0[0][b][j] = ho;
  write_ht(g_h0t, b, j, o1, o2);
}

// ---------------- per-step kernels ----------------
// 384 blocks. bid = mt*192 + mat*64 + bn  (partner m-tiles at delta=192 ->
// same XCD -> shared-W L2 hits). mat: 0 gi1, 1 gh0, 2 gh1.
__global__ __launch_bounds__(NTHR, 3) void k_mm(
    const float* __restrict__ b_ih1, const float* __restrict__ b_hh0,
    const float* __restrict__ b_hh1) {
  __shared__ __align__(16) unsigned short lds[2 * WBUF];
  const int bid = blockIdx.x;
  const int mt = bid / 192, r = bid % 192;
  const int mat = r >> 6, bn = r & 63;
  const unsigned short* At = (mat == 2) ? &g_h1t[0][0][0][0][0] : &g_h0t[0][0][0][0][0];
  const unsigned short* Wt = &g_wt[mat][bn][0][0][0][0][0];
  const float* bias = (mat == 0) ? b_ih1 : (mat == 1) ? b_hh0 : b_hh1;
  float* C = (mat == 0) ? &g_gi1[0][0] : (mat == 1) ? &g_gh0b[0][0] : &g_gh1b[0][0];
  mm_tile(At, Wt, bias, C, mt * 128, bn * MMN, lds);
}

// GRU1(t) + logits + sample + GRU0(t+1). One batch row per block.
__global__ __launch_bounds__(NTHR) void k_fuse(
    int t, const float* __restrict__ w_out, const float* __restrict__ b_out,
    float* __restrict__ out) {
  __shared__ __align__(16) float s_h[HH];
  __shared__ float s_log[32];
  __shared__ float s_score[32];
  __shared__ int s_tok;
  const int b = blockIdx.x, tid = threadIdx.x, j = tid << 2;
  const int pw = t & 1, pr = pw ^ 1;

  {
    const float* __restrict__ gi = g_gi1[b];
    const float* __restrict__ gh = g_gh1b[b];
    f4 ir = *(const f4*)&gi[j];
    f4 iz = *(const f4*)&gi[j + HH];
    f4 in_ = *(const f4*)&gi[j + 2 * HH];
    f4 hr = *(const f4*)&gh[j];
    f4 hz = *(const f4*)&gh[j + HH];
    f4 hn = *(const f4*)&gh[j + 2 * HH];
    f4 hp = *(const f4*)&g_h1[pr][b][j];
    f4 ho;
    u16x4 o1, o2;
#pragma unroll
    for (int c = 0; c < 4; ++c) {
      ho[c] = gru_h(ir[c], hr[c], iz[c], hz[c], in_[c], hn[c], hp[c]);
      unsigned short a, bb2;
      split2(ho[c], a, bb2);
      o1[c] = a; o2[c] = bb2;
    }
    *(f4*)&g_h1[pw][b][j] = ho;
    *(f4*)&s_h[j] = ho;
    write_ht(g_h1t, b, j, o1, o2);
  }
  __syncthreads();

  {
    const int v = tid >> 3, ks = tid & 7;
    float part = 0.f;
    if (v < VV) {
      const float* __restrict__ wrow = w_out + v * HH + ks * 128;
      const float* __restrict__ hh = s_h + ks * 128;
#pragma unroll 8
      for (int i = 0; i < 128; i += 4) {
        f4 wv = *(const f4*)&wrow[i];
        f4 hv = *(const f4*)&hh[i];
        part += hv[0] * wv[0] + hv[1] * wv[1] + hv[2] * wv[2] + hv[3] * wv[3];
      }
    }
    part += __shfl_xor(part, 1);
    part += __shfl_xor(part, 2);
    part += __shfl_xor(part, 4);
    if (v < VV && ks == 0) s_log[v] = part;
  }
  __syncthreads();

  if (tid < VV) {
    float logit = s_log[tid] + b_out[tid];
    out[(size_t)b * (TT * VV) + (size_t)t * VV + tid] = logit;
    uint2 kt = tf2x32(0u, 42u, 0u, (unsigned)t);
    uint2 rr = tf2x32(kt.x, kt.y, 0u, (unsigned)(b * VV + tid));
    unsigned bits = rr.x ^ rr.y;
    float uf = __uint_as_float((bits >> 9) | 0x3f800000u) - 1.0f;
    if (uf <= 0.0f) uf = 1.17549435e-38f;  // finfo(f32).tiny
    s_score[tid] = logit - logf(-logf(uf));
  }
  __syncthreads();
  if (tid == 0) {
    float best = s_score[0];
    int bv = 0;
    for (int vv = 1; vv < VV; ++vv) {
      float s = s_score[vv];
      if (s > best) { best = s; bv = vv; }  // strict >: first max
    }
    s_tok = bv;
    out[TOKBASE + (size_t)b * TT + t] = (float)bv;
  }
  __syncthreads();

  {
    const int tok = s_tok;
    const float* __restrict__ gi = g_P0[tok];
    const float* __restrict__ gh = g_gh0b[b];
    f4 ir = *(const f4*)&gi[j];
    f4 iz = *(const f4*)&gi[j + HH];
    f4 in_ = *(const f4*)&gi[j + 2 * HH];
    f4 hr = *(const f4*)&gh[j];
    f4 hz = *(const f4*)&gh[j + HH];
    f4 hn = *(const f4*)&gh[j + 2 * HH];
    f4 hp = *(const f4*)&g_h0[pw][b][j];
    f4 ho;
    u16x4 o1, o2;
#pragma unroll
    for (int c = 0; c < 4; ++c) {
      ho[c] = gru_h(ir[c], hr[c], iz[c], hz[c], in_[c], hn[c], hp[c]);
      unsigned short a, bb2;
      split2(ho[c], a, bb2);
      o1[c] = a; o2[c] = bb2;
    }
    *(f4*)&g_h0[pr][b][j] = ho;
    write_ht(g_h0t, b, j, o1, o2);
  }
}

extern "C" void kernel_launch(void* const* d_in, const int* in_sizes, int n_in,
                              void* d_out, int out_size, void* d_ws, size_t ws_size,
                              hipStream_t stream) {
  (void)in_sizes; (void)n_in; (void)d_ws; (void)ws_size; (void)out_size;
  const float* z     = (const float*)d_in[0];
  const float* emb   = (const float*)d_in[1];
  const float* w_zh  = (const float*)d_in[2];
  const float* b_zh  = (const float*)d_in[3];
  const float* w_ih0 = (const float*)d_in[4];
  const float* w_hh0 = (const float*)d_in[5];
  const float* b_ih0 = (const float*)d_in[6];
  const float* b_hh0 = (const float*)d_in[7];
  const float* w_ih1 = (const float*)d_in[8];
  const float* w_hh1 = (const float*)d_in[9];
  const float* b_ih1 = (const float*)d_in[10];
  const float* b_hh1 = (const float*)d_in[11];
  const float* w_out = (const float*)d_in[12];
  const float* b_out = (const float*)d_in[13];
  float* out = (float*)d_out;

  k_setup1<<<dim3(176), dim3(NTHR), 0, stream>>>(z, w_zh, b_zh, emb, w_ih0, b_ih0);
  k_splitw<<<dim3(4608), dim3(NTHR), 0, stream>>>(w_ih1, w_hh0, w_hh1);
  k_splith<<<dim3(512), dim3(NTHR), 0, stream>>>();
  k_mm_init<<<dim3(128), dim3(NTHR), 0, stream>>>(b_hh0);
  k_gate0_init<<<dim3(BB), dim3(NTHR), 0, stream>>>();

  for (int t = 0; t < TT; ++t) {
    k_mm<<<dim3(384), dim3(NTHR), 0, stream>>>(b_ih1, b_hh0, b_hh1);
    k_fuse<<<dim3(BB), dim3(NTHR), 0, stream>>>(t, w_out, b_out, out);
  }
}

// Round 11
// 16726.183 us; speedup vs baseline: 1.0588x; 1.0588x over previous
//
#include <hip/hip_runtime.h>

#define BB 256
#define HH 1024
#define EE 256
#define VV 28
#define ZZ 1024
#define TT 512
#define G3 3072
#define NTHR 256
#define TOKBASE (BB * TT * VV)

#define BM 64
#define BN 64
#define KT 32

// k_mm tile: 256(M) x 48(N) x 512(K-half); 2 kh x 3 mats x 64 bn = 384 blocks
#define MMN 48
#define NBN 64                      // 3072 / 48

typedef float f4 __attribute__((ext_vector_type(4)));
typedef float f32x4 __attribute__((ext_vector_type(4)));
typedef _Float16 f16x8 __attribute__((ext_vector_type(8)));   // 8 fp16 = 4 VGPR
typedef unsigned short u16x4 __attribute__((ext_vector_type(4)));
typedef unsigned short u16x8 __attribute__((ext_vector_type(8)));

#define RES_SCALE 512.0f
#define INV_RES (1.0f / 512.0f)

// ---- persistent state (fully rewritten every call; deterministic) ----
__device__ __align__(16) float g_h0[2][BB][HH];
__device__ __align__(16) float g_h1[2][BB][HH];
// K-half partial sums: [kh][mat][b][col]; mat 0 = gi1, 1 = gh0, 2 = gh1
__device__ __align__(16) float g_part[2][3][BB][G3];
__device__ __align__(16) float g_P0[VV][G3];
// Tiled (staging-order) fp16 2-split operands. ks = k-block of 32, s = split,
// kk = 8-wide k chunk. Split 1 = fp16(x); split 2 = fp16((x - x1)*512).
__device__ __align__(16) unsigned short g_h0t[32][2][4][BB][8];   // 1 MB
__device__ __align__(16) unsigned short g_h1t[32][2][4][BB][8];   // 1 MB
// mat 0 = w_ih1, 1 = w_hh0, 2 = w_hh1; bn = 48-col tile
__device__ __align__(16) unsigned short g_wt[3][NBN][32][2][4][MMN][8];  // 37.7 MB

// ---- threefry2x32, JAX-exact (20 rounds) ----
__device__ __forceinline__ uint2 tf2x32(unsigned k0, unsigned k1,
                                        unsigned x0, unsigned x1) {
  unsigned ks2 = k0 ^ k1 ^ 0x1BD11BDAu;
  unsigned ksl[3] = {k0, k1, ks2};
  x0 += k0; x1 += k1;
#pragma unroll
  for (int g = 0; g < 5; ++g) {
    const int r0 = (g & 1) ? 17 : 13;
    const int r1 = (g & 1) ? 29 : 15;
    const int r2 = (g & 1) ? 16 : 26;
    const int r3 = (g & 1) ? 24 : 6;
    x0 += x1; x1 = (x1 << r0) | (x1 >> (32 - r0)); x1 ^= x0;
    x0 += x1; x1 = (x1 << r1) | (x1 >> (32 - r1)); x1 ^= x0;
    x0 += x1; x1 = (x1 << r2) | (x1 >> (32 - r2)); x1 ^= x0;
    x0 += x1; x1 = (x1 << r3) | (x1 >> (32 - r3)); x1 ^= x0;
    x0 += ksl[(g + 1) % 3];
    x1 += ksl[(g + 2) % 3] + (unsigned)(g + 1);
  }
  return make_uint2(x0, x1);
}

__device__ __forceinline__ float sigf(float x) {
  return 1.0f / (1.0f + expf(-x));
}

__device__ __forceinline__ float gru_h(float i_r, float h_r, float i_z, float h_z,
                                       float i_n, float h_n, float hprev) {
  float r  = sigf(i_r + h_r);
  float zg = sigf(i_z + h_z);
  float n  = tanhf(i_n + r * h_n);
  return (1.0f - zg) * n + zg * hprev;
}

// fp16 2-way split: x ~= x1 + x2/512, residual stored scaled to dodge subnormals
__device__ __forceinline__ void split2(float x, unsigned short& a,
                                       unsigned short& b) {
  _Float16 h1 = (_Float16)x;
  _Float16 h2 = (_Float16)((x - (float)h1) * RES_SCALE);
  a = __builtin_bit_cast(unsigned short, h1);
  b = __builtin_bit_cast(unsigned short, h2);
}

// async global->LDS, 16B per lane
__device__ __forceinline__ void gload16(unsigned short* l, const unsigned short* g) {
  __builtin_amdgcn_global_load_lds(
      (const __attribute__((address_space(1))) unsigned int*)(g),
      (__attribute__((address_space(3))) unsigned int*)(l), 16, 0, 0);
}

// ---------------- fp32 tiled GEMM (setup only) ----------------
__device__ __forceinline__ void gemm_unit(
    const float* __restrict__ At, int lda, int rows_valid,
    const float* __restrict__ Wt, int ldw,
    const float* __restrict__ bias,
    float* __restrict__ Ct, int ldc,
    int K, int mode,
    float (&As)[BM][KT + 4], float (&Ws)[KT][BN + 4]) {
  const int tid = threadIdx.x;
  const int tx = tid & 15, ty = tid >> 4;
  f4 acc0 = {0.f, 0.f, 0.f, 0.f};
  f4 acc1 = {0.f, 0.f, 0.f, 0.f};
  f4 acc2 = {0.f, 0.f, 0.f, 0.f};
  f4 acc3 = {0.f, 0.f, 0.f, 0.f};

  for (int kb = 0; kb < K; kb += KT) {
#pragma unroll
    for (int l = 0; l < 2; ++l) {
      int f = tid + l * NTHR;
      int r = f >> 3, kq = (f & 7) << 2;
      f4 v = {0.f, 0.f, 0.f, 0.f};
      if (r < rows_valid) v = *(const f4*)(At + r * lda + kb + kq);
      *(f4*)&As[r][kq] = v;
    }
#pragma unroll
    for (int l = 0; l < 2; ++l) {
      int f = tid + l * NTHR;
      int nr = f >> 3, kq = (f & 7) << 2;
      f4 v = *(const f4*)(Wt + nr * ldw + kb + kq);
      Ws[kq + 0][nr] = v[0];
      Ws[kq + 1][nr] = v[1];
      Ws[kq + 2][nr] = v[2];
      Ws[kq + 3][nr] = v[3];
    }
    __syncthreads();
#pragma unroll
    for (int kk = 0; kk < KT; kk += 4) {
      f4 a0 = *(const f4*)&As[(ty << 2) + 0][kk];
      f4 a1 = *(const f4*)&As[(ty << 2) + 1][kk];
      f4 a2 = *(const f4*)&As[(ty << 2) + 2][kk];
      f4 a3 = *(const f4*)&As[(ty << 2) + 3][kk];
      f4 b0 = *(const f4*)&Ws[kk + 0][tx << 2];
      f4 b1 = *(const f4*)&Ws[kk + 1][tx << 2];
      f4 b2 = *(const f4*)&Ws[kk + 2][tx << 2];
      f4 b3 = *(const f4*)&Ws[kk + 3][tx << 2];
      acc0 += b0 * a0[0]; acc0 += b1 * a0[1]; acc0 += b2 * a0[2]; acc0 += b3 * a0[3];
      acc1 += b0 * a1[0]; acc1 += b1 * a1[1]; acc1 += b2 * a1[2]; acc1 += b3 * a1[3];
      acc2 += b0 * a2[0]; acc2 += b1 * a2[1]; acc2 += b2 * a2[2]; acc2 += b3 * a2[3];
      acc3 += b0 * a3[0]; acc3 += b1 * a3[1]; acc3 += b2 * a3[2]; acc3 += b3 * a3[3];
    }
    __syncthreads();
  }

  f4 accs[4] = {acc0, acc1, acc2, acc3};
#pragma unroll
  for (int i = 0; i < 4; ++i) {
    int r = (ty << 2) + i;
    if (r < rows_valid) {
#pragma unroll
      for (int j = 0; j < 4; ++j) {
        int c = (tx << 2) + j;
        float v = accs[i][j] + bias[c];
        if (mode == 1) v = tanhf(v);
        Ct[r * ldc + c] = v;
      }
    }
  }
}

// ------------- MFMA tile 256(M) x 48(N) x 512(K-half), fp16 2-split/3-product -------------
// 4 waves: wave wr owns rows [wr*64,+64) x 48 cols = 4 m-frags x 3 n-frags.
// LDS = exact image of tiled global arrays (linear staging, conflict-free
// ds_read_b128). Writes PARTIAL sums (no bias) to g_part; k_fuse reduces.
#define A_CH (2 * 4 * 256)          // 2048 chunks of 16B per ks
#define W_CH (2 * 4 * MMN)          // 384 chunks
#define BUFSZ ((A_CH + W_CH) * 8)   // ushorts per buffer (38 KB)
#define KSH 16                      // ks blocks per K-half

__device__ __forceinline__ void mm_tile(
    const unsigned short* __restrict__ At,  // g_h0t / g_h1t base
    const unsigned short* __restrict__ Wt,  // &g_wt[mat][bn][0][0][0][0][0]
    float* __restrict__ C,                  // &g_part[kh][mat][0][0]
    int n0, int ks0, unsigned short* lds) {
  const int tid = threadIdx.x;
  const int wr = tid >> 6, lane = tid & 63;
  const int lr = lane & 15, lk8 = lane >> 4;   // k8 slot 0..3

  f32x4 acc1[4][3] = {};
  f32x4 accR[4][3] = {};

  auto stage = [&](int buf, int ks) {
    unsigned short* lA = lds + buf * BUFSZ;
    unsigned short* lW = lA + A_CH * 8;
    // A: 2048 chunks, 8 rounds; global layout == LDS layout -> fully linear.
    const unsigned short* abase = At + (size_t)ks * (A_CH * 8);
#pragma unroll
    for (int r = 0; r < 8; ++r) {
      int j = r * NTHR + tid;
      gload16(lA + j * 8, abase + (size_t)j * 8);
    }
    // W: 384 chunks = 1.5 rounds, linear within the (mat,bn,ks) tile.
    const unsigned short* wbase = Wt + (size_t)ks * (W_CH * 8);
    gload16(lW + tid * 8, wbase + (size_t)tid * 8);
    if (tid < W_CH - NTHR) {
      int j = NTHR + tid;
      gload16(lW + j * 8, wbase + (size_t)j * 8);
    }
  };

  stage(0, ks0);
  int cur = 0;
  for (int ks = ks0; ks < ks0 + KSH; ++ks) {
    __syncthreads();                       // buf[cur] staged & old reads done
    if (ks + 1 < ks0 + KSH) stage(cur ^ 1, ks + 1);
    const unsigned short* lA = lds + cur * BUFSZ;
    const unsigned short* lW = lA + A_CH * 8;
    f16x8 a[4][2], b[3][2];
#pragma unroll
    for (int mi = 0; mi < 4; ++mi)
#pragma unroll
      for (int s = 0; s < 2; ++s)
        a[mi][s] = *(const f16x8*)(lA + (((s << 2) | lk8) * 256 + wr * 64 + mi * 16 + lr) * 8);
#pragma unroll
    for (int ni = 0; ni < 3; ++ni)
#pragma unroll
      for (int s = 0; s < 2; ++s)
        b[ni][s] = *(const f16x8*)(lW + (((s << 2) | lk8) * MMN + ni * 16 + lr) * 8);
#pragma unroll
    for (int mi = 0; mi < 4; ++mi)
#pragma unroll
      for (int ni = 0; ni < 3; ++ni) {
        acc1[mi][ni] = __builtin_amdgcn_mfma_f32_16x16x32_f16(a[mi][0], b[ni][0], acc1[mi][ni], 0, 0, 0);
        accR[mi][ni] = __builtin_amdgcn_mfma_f32_16x16x32_f16(a[mi][0], b[ni][1], accR[mi][ni], 0, 0, 0);
        accR[mi][ni] = __builtin_amdgcn_mfma_f32_16x16x32_f16(a[mi][1], b[ni][0], accR[mi][ni], 0, 0, 0);
      }
    cur ^= 1;
  }

  // store partials: D layout col=lane&15, row=(lane>>4)*4+reg
#pragma unroll
  for (int mi = 0; mi < 4; ++mi) {
    int rowb = wr * 64 + mi * 16 + ((lane >> 4) << 2);
#pragma unroll
    for (int ni = 0; ni < 3; ++ni) {
      int col = n0 + ni * 16 + lr;
#pragma unroll
      for (int r = 0; r < 4; ++r)
        C[(size_t)(rowb + r) * G3 + col] = acc1[mi][ni][r] + accR[mi][ni][r] * INV_RES;
    }
  }
}

// write one row's 4 consecutive k of both splits into a tiled h array
__device__ __forceinline__ void write_ht(unsigned short (*ht)[2][4][BB][8],
                                         int row, int k0,
                                         u16x4 o1, u16x4 o2) {
  const int ks = k0 >> 5, kk = (k0 >> 3) & 3, e0 = k0 & 7;
  *(u16x4*)&ht[ks][0][kk][row][e0] = o1;
  *(u16x4*)&ht[ks][1][kk][row][e0] = o2;
}

// ---------------- setup kernels ----------------
__global__ __launch_bounds__(NTHR) void k_setup1(
    const float* __restrict__ z, const float* __restrict__ w_zh,
    const float* __restrict__ b_zh, const float* __restrict__ emb,
    const float* __restrict__ w_ih0, const float* __restrict__ b_ih0) {
  __shared__ __align__(16) float As[BM][KT + 4];
  __shared__ __align__(16) float Ws[KT][BN + 4];
  const int bid = blockIdx.x;
  if (bid < 128) {
    int m0 = (bid >> 5) * BM;
    int n0 = (bid & 31) * BN;
    float* Cb;
    int col;
    if (n0 < HH) { Cb = &g_h0[1][0][0]; col = n0; }
    else         { Cb = &g_h1[1][0][0]; col = n0 - HH; }
    gemm_unit(z + m0 * ZZ, ZZ, BM, w_zh + n0 * ZZ, ZZ, b_zh + n0,
              Cb + m0 * HH + col, HH, ZZ, 1, As, Ws);
  } else {
    int n0 = (bid - 128) * BN;
    gemm_unit(emb, EE, VV, w_ih0 + n0 * EE, EE, b_ih0 + n0,
              &g_P0[0][0] + n0, G3, EE, 0, As, Ws);
  }
}

// split + tile the 3 recurrent weight matrices -> g_wt (48-col tiles).
__global__ __launch_bounds__(NTHR) void k_splitw(
    const float* __restrict__ w_ih1, const float* __restrict__ w_hh0,
    const float* __restrict__ w_hh1) {
  unsigned u = blockIdx.x * NTHR + threadIdx.x;   // < 1,179,648
  int row = u % MMN;
  unsigned v = u / MMN;
  int kk = v & 3, ks = (v >> 2) & 31;
  unsigned rem = v >> 7;                           // mat*NBN + bn
  int mat = rem / NBN, bn = rem % NBN;
  const float* src = (mat == 0) ? w_ih1 : (mat == 1) ? w_hh0 : w_hh1;
  const float* p = src + (size_t)(bn * MMN + row) * HH + ks * 32 + kk * 8;
  f4 v0 = *(const f4*)p;
  f4 v1 = *(const f4*)(p + 4);
  u16x8 o1, o2;
#pragma unroll
  for (int c = 0; c < 8; ++c) {
    float x = (c < 4) ? v0[c] : v1[c - 4];
    unsigned short a, b;
    split2(x, a, b);
    o1[c] = a; o2[c] = b;
  }
  *(u16x8*)&g_wt[mat][bn][ks][0][kk][row][0] = o1;
  *(u16x8*)&g_wt[mat][bn][ks][1][kk][row][0] = o2;
}

// split h0init/h1init into tiled g_h0t/g_h1t. One thread per (mat,row,kquad).
__global__ __launch_bounds__(NTHR) void k_splith() {
  unsigned e = blockIdx.x * NTHR + threadIdx.x;   // < 131072
  int mat = e >> 16, r = (e >> 8) & 255, k0 = (e & 255) << 2;
  const float* src = (mat == 0) ? &g_h0[1][0][0] : &g_h1[1][0][0];
  f4 v = *(const f4*)(src + (size_t)r * HH + k0);
  u16x4 o1, o2;
#pragma unroll
  for (int c = 0; c < 4; ++c) {
    unsigned short a, b;
    split2(v[c], a, b);
    o1[c] = a; o2[c] = b;
  }
  write_ht((mat == 0) ? g_h0t : g_h1t, r, k0, o1, o2);
}

// gh0(-1) partials = h0init @ w_hh0^T : 2 kh x 64 bn (mat 1 only)
__global__ __launch_bounds__(NTHR, 2) void k_mm_init() {
  __shared__ __align__(16) unsigned short lds[2 * BUFSZ];
  int kh = blockIdx.x >> 6, bn = blockIdx.x & 63;
  mm_tile(&g_h0t[0][0][0][0][0], &g_wt[1][bn][0][0][0][0][0],
          &g_part[kh][1][0][0], bn * MMN, kh * KSH, lds);
}

// gate0 for t=0 (token = SOS = 1)
__global__ __launch_bounds__(NTHR) void k_gate0_init(
    const float* __restrict__ b_hh0) {
  const int b = blockIdx.x, tid = threadIdx.x, j = tid << 2;
  const float* __restrict__ gi = g_P0[1];
  const float* __restrict__ ghA = g_part[0][1][b];
  const float* __restrict__ ghB = g_part[1][1][b];
  f4 ir = *(const f4*)&gi[j];
  f4 iz = *(const f4*)&gi[j + HH];
  f4 in_ = *(const f4*)&gi[j + 2 * HH];
  f4 hr = (*(const f4*)&ghA[j] + *(const f4*)&ghB[j]) + *(const f4*)&b_hh0[j];
  f4 hz = (*(const f4*)&ghA[j + HH] + *(const f4*)&ghB[j + HH]) + *(const f4*)&b_hh0[j + HH];
  f4 hn = (*(const f4*)&ghA[j + 2 * HH] + *(const f4*)&ghB[j + 2 * HH]) + *(const f4*)&b_hh0[j + 2 * HH];
  f4 hp = *(const f4*)&g_h0[1][b][j];
  f4 ho;
  u16x4 o1, o2;
#pragma unroll
  for (int c = 0; c < 4; ++c) {
    ho[c] = gru_h(ir[c], hr[c], iz[c], hz[c], in_[c], hn[c], hp[c]);
    unsigned short a, bb2;
    split2(ho[c], a, bb2);
    o1[c] = a; o2[c] = bb2;
  }
  *(f4*)&g_h0[0][b][j] = ho;
  write_ht(g_h0t, b, j, o1, o2);
}

// ---------------- per-step kernels ----------------
// 384 blocks. bid = kh*192 + mat*64 + bn. mat: 0 gi1, 1 gh0, 2 gh1.
__global__ __launch_bounds__(NTHR, 2) void k_mm() {
  __shared__ __align__(16) unsigned short lds[2 * BUFSZ];
  const int bid = blockIdx.x;
  const int kh = bid / 192, r = bid % 192;
  const int mat = r >> 6, bn = r & 63;
  const unsigned short* At = (mat == 2) ? &g_h1t[0][0][0][0][0] : &g_h0t[0][0][0][0][0];
  const unsigned short* Wt = &g_wt[mat][bn][0][0][0][0][0];
  mm_tile(At, Wt, &g_part[kh][mat][0][0], bn * MMN, kh * KSH, lds);
}

// GRU1(t) + logits + sample + GRU0(t+1). One batch row per block.
__global__ __launch_bounds__(NTHR) void k_fuse(
    int t, const float* __restrict__ w_out, const float* __restrict__ b_out,
    const float* __restrict__ b_ih1, const float* __restrict__ b_hh0,
    const float* __restrict__ b_hh1, float* __restrict__ out) {
  __shared__ __align__(16) float s_h[HH];
  __shared__ float s_log[32];
  __shared__ float s_score[32];
  __shared__ int s_tok;
  const int b = blockIdx.x, tid = threadIdx.x, j = tid << 2;
  const int pw = t & 1, pr = pw ^ 1;

  {
    const float* __restrict__ giA = g_part[0][0][b];
    const float* __restrict__ giB = g_part[1][0][b];
    const float* __restrict__ ghA = g_part[0][2][b];
    const float* __restrict__ ghB = g_part[1][2][b];
    f4 ir = (*(const f4*)&giA[j] + *(const f4*)&giB[j]) + *(const f4*)&b_ih1[j];
    f4 iz = (*(const f4*)&giA[j + HH] + *(const f4*)&giB[j + HH]) + *(const f4*)&b_ih1[j + HH];
    f4 in_ = (*(const f4*)&giA[j + 2 * HH] + *(const f4*)&giB[j + 2 * HH]) + *(const f4*)&b_ih1[j + 2 * HH];
    f4 hr = (*(const f4*)&ghA[j] + *(const f4*)&ghB[j]) + *(const f4*)&b_hh1[j];
    f4 hz = (*(const f4*)&ghA[j + HH] + *(const f4*)&ghB[j + HH]) + *(const f4*)&b_hh1[j + HH];
    f4 hn = (*(const f4*)&ghA[j + 2 * HH] + *(const f4*)&ghB[j + 2 * HH]) + *(const f4*)&b_hh1[j + 2 * HH];
    f4 hp = *(const f4*)&g_h1[pr][b][j];
    f4 ho;
    u16x4 o1, o2;
#pragma unroll
    for (int c = 0; c < 4; ++c) {
      ho[c] = gru_h(ir[c], hr[c], iz[c], hz[c], in_[c], hn[c], hp[c]);
      unsigned short a, bb2;
      split2(ho[c], a, bb2);
      o1[c] = a; o2[c] = bb2;
    }
    *(f4*)&g_h1[pw][b][j] = ho;
    *(f4*)&s_h[j] = ho;
    write_ht(g_h1t, b, j, o1, o2);
  }
  __syncthreads();

  {
    const int v = tid >> 3, ks = tid & 7;
    float part = 0.f;
    if (v < VV) {
      const float* __restrict__ wrow = w_out + v * HH + ks * 128;
      const float* __restrict__ hh = s_h + ks * 128;
#pragma unroll 8
      for (int i = 0; i < 128; i += 4) {
        f4 wv = *(const f4*)&wrow[i];
        f4 hv = *(const f4*)&hh[i];
        part += hv[0] * wv[0] + hv[1] * wv[1] + hv[2] * wv[2] + hv[3] * wv[3];
      }
    }
    part += __shfl_xor(part, 1);
    part += __shfl_xor(part, 2);
    part += __shfl_xor(part, 4);
    if (v < VV && ks == 0) s_log[v] = part;
  }
  __syncthreads();

  if (tid < VV) {
    float logit = s_log[tid] + b_out[tid];
    out[(size_t)b * (TT * VV) + (size_t)t * VV + tid] = logit;
    uint2 kt = tf2x32(0u, 42u, 0u, (unsigned)t);
    uint2 rr = tf2x32(kt.x, kt.y, 0u, (unsigned)(b * VV + tid));
    unsigned bits = rr.x ^ rr.y;
    float uf = __uint_as_float((bits >> 9) | 0x3f800000u) - 1.0f;
    if (uf <= 0.0f) uf = 1.17549435e-38f;  // finfo(f32).tiny
    s_score[tid] = logit - logf(-logf(uf));
  }
  __syncthreads();
  if (tid == 0) {
    float best = s_score[0];
    int bv = 0;
    for (int vv = 1; vv < VV; ++vv) {
      float s = s_score[vv];
      if (s > best) { best = s; bv = vv; }  // strict >: first max
    }
    s_tok = bv;
    out[TOKBASE + (size_t)b * TT + t] = (float)bv;
  }
  __syncthreads();

  {
    const int tok = s_tok;
    const float* __restrict__ gi = g_P0[tok];
    const float* __restrict__ ghA = g_part[0][1][b];
    const float* __restrict__ ghB = g_part[1][1][b];
    f4 ir = *(const f4*)&gi[j];
    f4 iz = *(const f4*)&gi[j + HH];
    f4 in_ = *(const f4*)&gi[j + 2 * HH];
    f4 hr = (*(const f4*)&ghA[j] + *(const f4*)&ghB[j]) + *(const f4*)&b_hh0[j];
    f4 hz = (*(const f4*)&ghA[j + HH] + *(const f4*)&ghB[j + HH]) + *(const f4*)&b_hh0[j + HH];
    f4 hn = (*(const f4*)&ghA[j + 2 * HH] + *(const f4*)&ghB[j + 2 * HH]) + *(const f4*)&b_hh0[j + 2 * HH];
    f4 hp = *(const f4*)&g_h0[pw][b][j];
    f4 ho;
    u16x4 o1, o2;
#pragma unroll
    for (int c = 0; c < 4; ++c) {
      ho[c] = gru_h(ir[c], hr[c], iz[c], hz[c], in_[c], hn[c], hp[c]);
      unsigned short a, bb2;
      split2(ho[c], a, bb2);
      o1[c] = a; o2[c] = bb2;
    }
    *(f4*)&g_h0[pr][b][j] = ho;
    write_ht(g_h0t, b, j, o1, o2);
  }
}

extern "C" void kernel_launch(void* const* d_in, const int* in_sizes, int n_in,
                              void* d_out, int out_size, void* d_ws, size_t ws_size,
                              hipStream_t stream) {
  (void)in_sizes; (void)n_in; (void)d_ws; (void)ws_size; (void)out_size;
  const float* z     = (const float*)d_in[0];
  const float* emb   = (const float*)d_in[1];
  const float* w_zh  = (const float*)d_in[2];
  const float* b_zh  = (const float*)d_in[3];
  const float* w_ih0 = (const float*)d_in[4];
  const float* w_hh0 = (const float*)d_in[5];
  const float* b_ih0 = (const float*)d_in[6];
  const float* b_hh0 = (const float*)d_in[7];
  const float* w_ih1 = (const float*)d_in[8];
  const float* w_hh1 = (const float*)d_in[9];
  const float* b_ih1 = (const float*)d_in[10];
  const float* b_hh1 = (const float*)d_in[11];
  const float* w_out = (const float*)d_in[12];
  const float* b_out = (const float*)d_in[13];
  float* out = (float*)d_out;

  k_setup1<<<dim3(176), dim3(NTHR), 0, stream>>>(z, w_zh, b_zh, emb, w_ih0, b_ih0);
  k_splitw<<<dim3(4608), dim3(NTHR), 0, stream>>>(w_ih1, w_hh0, w_hh1);
  k_splith<<<dim3(512), dim3(NTHR), 0, stream>>>();
  k_mm_init<<<dim3(128), dim3(NTHR), 0, stream>>>();
  k_gate0_init<<<dim3(BB), dim3(NTHR), 0, stream>>>(b_hh0);

  for (int t = 0; t < TT; ++t) {
    k_mm<<<dim3(384), dim3(NTHR), 0, stream>>>();
    k_fuse<<<dim3(BB), dim3(NTHR), 0, stream>>>(t, w_out, b_out, b_ih1, b_hh0,
                                                b_hh1, out);
  }
}

// Round 12
// 15843.665 us; speedup vs baseline: 1.1178x; 1.0557x over previous
//
#include <hip/hip_runtime.h>

#define BB 256
#define HH 1024
#define EE 256
#define VV 28
#define ZZ 1024
#define TT 512
#define G3 3072
#define NTHR 256
#define TOKBASE (BB * TT * VV)

#define BM 64
#define BN 64
#define KT 32

// k_mm tile: 128(M) x 48(N), 2 m-tiles x 64 bn-tiles x 3 mats = 384 blocks
#define MMN 48
#define NBN 64                      // 3072 / 48

typedef float f4 __attribute__((ext_vector_type(4)));
typedef float f32x4 __attribute__((ext_vector_type(4)));
typedef _Float16 f16x8 __attribute__((ext_vector_type(8)));   // 8 fp16 = 4 VGPR
typedef unsigned short u16x4 __attribute__((ext_vector_type(4)));
typedef unsigned short u16x8 __attribute__((ext_vector_type(8)));

#define RES_SCALE 512.0f
#define INV_RES (1.0f / 512.0f)

// ---- persistent state (fully rewritten every call; deterministic) ----
__device__ __align__(16) float g_h0[2][BB][HH];
__device__ __align__(16) float g_h1[2][BB][HH];
__device__ __align__(16) float g_gh0b[BB][G3];
__device__ __align__(16) float g_gh1b[BB][G3];
__device__ __align__(16) float g_gi1[BB][G3];
__device__ __align__(16) float g_P0[VV][G3];
// Tiled (staging-order) fp16 2-split operands. ks = k-block of 32, s = split,
// kk = 8-wide k chunk. Split 1 = fp16(x); split 2 = fp16((x - x1)*512).
__device__ __align__(16) unsigned short g_h0t[32][2][4][BB][8];   // 1 MB
__device__ __align__(16) unsigned short g_h1t[32][2][4][BB][8];   // 1 MB
// mat 0 = w_ih1, 1 = w_hh0, 2 = w_hh1; bn = 48-col tile
__device__ __align__(16) unsigned short g_wt[3][NBN][32][2][4][MMN][8];  // 37.7 MB

// ---- threefry2x32, JAX-exact (20 rounds) ----
__device__ __forceinline__ uint2 tf2x32(unsigned k0, unsigned k1,
                                        unsigned x0, unsigned x1) {
  unsigned ks2 = k0 ^ k1 ^ 0x1BD11BDAu;
  unsigned ksl[3] = {k0, k1, ks2};
  x0 += k0; x1 += k1;
#pragma unroll
  for (int g = 0; g < 5; ++g) {
    const int r0 = (g & 1) ? 17 : 13;
    const int r1 = (g & 1) ? 29 : 15;
    const int r2 = (g & 1) ? 16 : 26;
    const int r3 = (g & 1) ? 24 : 6;
    x0 += x1; x1 = (x1 << r0) | (x1 >> (32 - r0)); x1 ^= x0;
    x0 += x1; x1 = (x1 << r1) | (x1 >> (32 - r1)); x1 ^= x0;
    x0 += x1; x1 = (x1 << r2) | (x1 >> (32 - r2)); x1 ^= x0;
    x0 += x1; x1 = (x1 << r3) | (x1 >> (32 - r3)); x1 ^= x0;
    x0 += ksl[(g + 1) % 3];
    x1 += ksl[(g + 2) % 3] + (unsigned)(g + 1);
  }
  return make_uint2(x0, x1);
}

__device__ __forceinline__ float sigf(float x) {
  return 1.0f / (1.0f + expf(-x));
}

__device__ __forceinline__ float gru_h(float i_r, float h_r, float i_z, float h_z,
                                       float i_n, float h_n, float hprev) {
  float r  = sigf(i_r + h_r);
  float zg = sigf(i_z + h_z);
  float n  = tanhf(i_n + r * h_n);
  return (1.0f - zg) * n + zg * hprev;
}

// fp16 2-way split: x ~= x1 + x2/512, residual stored scaled to dodge subnormals
__device__ __forceinline__ void split2(float x, unsigned short& a,
                                       unsigned short& b) {
  _Float16 h1 = (_Float16)x;
  _Float16 h2 = (_Float16)((x - (float)h1) * RES_SCALE);
  a = __builtin_bit_cast(unsigned short, h1);
  b = __builtin_bit_cast(unsigned short, h2);
}

// async global->LDS, 16B per lane
__device__ __forceinline__ void gload16(unsigned short* l, const unsigned short* g) {
  __builtin_amdgcn_global_load_lds(
      (const __attribute__((address_space(1))) unsigned int*)(g),
      (__attribute__((address_space(3))) unsigned int*)(l), 16, 0, 0);
}

// ---------------- fp32 tiled GEMM (setup only) ----------------
__device__ __forceinline__ void gemm_unit(
    const float* __restrict__ At, int lda, int rows_valid,
    const float* __restrict__ Wt, int ldw,
    const float* __restrict__ bias,
    float* __restrict__ Ct, int ldc,
    int K, int mode,
    float (&As)[BM][KT + 4], float (&Ws)[KT][BN + 4]) {
  const int tid = threadIdx.x;
  const int tx = tid & 15, ty = tid >> 4;
  f4 acc0 = {0.f, 0.f, 0.f, 0.f};
  f4 acc1 = {0.f, 0.f, 0.f, 0.f};
  f4 acc2 = {0.f, 0.f, 0.f, 0.f};
  f4 acc3 = {0.f, 0.f, 0.f, 0.f};

  for (int kb = 0; kb < K; kb += KT) {
#pragma unroll
    for (int l = 0; l < 2; ++l) {
      int f = tid + l * NTHR;
      int r = f >> 3, kq = (f & 7) << 2;
      f4 v = {0.f, 0.f, 0.f, 0.f};
      if (r < rows_valid) v = *(const f4*)(At + r * lda + kb + kq);
      *(f4*)&As[r][kq] = v;
    }
#pragma unroll
    for (int l = 0; l < 2; ++l) {
      int f = tid + l * NTHR;
      int nr = f >> 3, kq = (f & 7) << 2;
      f4 v = *(const f4*)(Wt + nr * ldw + kb + kq);
      Ws[kq + 0][nr] = v[0];
      Ws[kq + 1][nr] = v[1];
      Ws[kq + 2][nr] = v[2];
      Ws[kq + 3][nr] = v[3];
    }
    __syncthreads();
#pragma unroll
    for (int kk = 0; kk < KT; kk += 4) {
      f4 a0 = *(const f4*)&As[(ty << 2) + 0][kk];
      f4 a1 = *(const f4*)&As[(ty << 2) + 1][kk];
      f4 a2 = *(const f4*)&As[(ty << 2) + 2][kk];
      f4 a3 = *(const f4*)&As[(ty << 2) + 3][kk];
      f4 b0 = *(const f4*)&Ws[kk + 0][tx << 2];
      f4 b1 = *(const f4*)&Ws[kk + 1][tx << 2];
      f4 b2 = *(const f4*)&Ws[kk + 2][tx << 2];
      f4 b3 = *(const f4*)&Ws[kk + 3][tx << 2];
      acc0 += b0 * a0[0]; acc0 += b1 * a0[1]; acc0 += b2 * a0[2]; acc0 += b3 * a0[3];
      acc1 += b0 * a1[0]; acc1 += b1 * a1[1]; acc1 += b2 * a1[2]; acc1 += b3 * a1[3];
      acc2 += b0 * a2[0]; acc2 += b1 * a2[1]; acc2 += b2 * a2[2]; acc2 += b3 * a2[3];
      acc3 += b0 * a3[0]; acc3 += b1 * a3[1]; acc3 += b2 * a3[2]; acc3 += b3 * a3[3];
    }
    __syncthreads();
  }

  f4 accs[4] = {acc0, acc1, acc2, acc3};
#pragma unroll
  for (int i = 0; i < 4; ++i) {
    int r = (ty << 2) + i;
    if (r < rows_valid) {
#pragma unroll
      for (int j = 0; j < 4; ++j) {
        int c = (tx << 2) + j;
        float v = accs[i][j] + bias[c];
        if (mode == 1) v = tanhf(v);
        Ct[r * ldc + c] = v;
      }
    }
  }
}

// ------------- MFMA tile 128(M) x 48(N), K=1024, fp16 2-split/3-product -------------
// 4 waves: wave wr owns rows [wr*32,+32) x 48 cols = 2 m-frags x 3 n-frags.
// TRIPLE-buffered LDS with counted vmcnt (T3/T4): stage(ks+1), stage(ks+2) stay
// in flight across the barrier; vmcnt never drains to 0 in the main loop.
// Per-stage VMEM ops per wave: waves 0-1 issue 6 (4 A + 2 W), waves 2-3 issue 5
// (4 A + 1 W) -> steady-state waits vmcnt(6)/vmcnt(5) retire exactly stage(ks).
// Buffers: compute reads ks%3; in-flight writes target (ks+1)%3,(ks+2)%3 - disjoint.
#define A_CH (2 * 4 * 128)          // 1024 chunks of 16B per ks
#define W_CH (2 * 4 * MMN)          // 384 chunks
#define BUFSZ ((A_CH + W_CH) * 8)   // ushorts per buffer (22 KB); x3 = 66 KB

__device__ __forceinline__ void mm_tile(
    const unsigned short* __restrict__ At,  // g_h0t / g_h1t base
    const unsigned short* __restrict__ Wt,  // &g_wt[mat][bn][0][0][0][0][0]
    const float* __restrict__ bias,
    float* __restrict__ C,                  // [BB][G3]
    int m0, int n0, unsigned short* lds) {
  const int tid = threadIdx.x;
  const int wr = tid >> 6, lane = tid & 63;
  const int lr = lane & 15, lk8 = lane >> 4;   // k8 slot 0..3
  const bool hiW = (tid < 128);                // waves 0,1: 6 loads/stage

  f32x4 acc1[2][3] = {};
  f32x4 accR[2][3] = {};

  auto stage = [&](unsigned short* lbuf, int ks) {
    unsigned short* lA = lbuf;
    unsigned short* lW = lbuf + A_CH * 8;
    const unsigned short* abase = At + (size_t)ks * (2 * 4 * BB * 8);
#pragma unroll
    for (int r = 0; r < 4; ++r) {
      int j = r * NTHR + tid;
      int skk = j >> 7, row = j & 127;
      gload16(lA + j * 8, abase + ((size_t)skk * BB + m0 + row) * 8);
    }
    const unsigned short* wbase = Wt + (size_t)ks * (W_CH * 8);
    gload16(lW + tid * 8, wbase + (size_t)tid * 8);
    if (tid < W_CH - NTHR) {                  // waves 0,1 only (128 threads)
      int j = NTHR + tid;
      gload16(lW + j * 8, wbase + (size_t)j * 8);
    }
  };

  auto compute = [&](const unsigned short* lbuf) {
    const unsigned short* lA = lbuf;
    const unsigned short* lW = lbuf + A_CH * 8;
    f16x8 a[2][2], b[3][2];
#pragma unroll
    for (int mi = 0; mi < 2; ++mi)
#pragma unroll
      for (int s = 0; s < 2; ++s)
        a[mi][s] = *(const f16x8*)(lA + (((s << 2) | lk8) * 128 + wr * 32 + mi * 16 + lr) * 8);
#pragma unroll
    for (int ni = 0; ni < 3; ++ni)
#pragma unroll
      for (int s = 0; s < 2; ++s)
        b[ni][s] = *(const f16x8*)(lW + (((s << 2) | lk8) * MMN + ni * 16 + lr) * 8);
    __builtin_amdgcn_s_setprio(1);
#pragma unroll
    for (int mi = 0; mi < 2; ++mi)
#pragma unroll
      for (int ni = 0; ni < 3; ++ni) {
        acc1[mi][ni] = __builtin_amdgcn_mfma_f32_16x16x32_f16(a[mi][0], b[ni][0], acc1[mi][ni], 0, 0, 0);
        accR[mi][ni] = __builtin_amdgcn_mfma_f32_16x16x32_f16(a[mi][0], b[ni][1], accR[mi][ni], 0, 0, 0);
        accR[mi][ni] = __builtin_amdgcn_mfma_f32_16x16x32_f16(a[mi][1], b[ni][0], accR[mi][ni], 0, 0, 0);
      }
    __builtin_amdgcn_s_setprio(0);
  };

  stage(lds, 0);
  stage(lds + BUFSZ, 1);
  for (int ks = 0; ks < 32; ++ks) {
    if (ks < 31) {
      if (hiW) asm volatile("s_waitcnt vmcnt(6)" ::: "memory");
      else     asm volatile("s_waitcnt vmcnt(5)" ::: "memory");
    } else {
      asm volatile("s_waitcnt vmcnt(0)" ::: "memory");
    }
    __builtin_amdgcn_s_barrier();
    compute(lds + (ks % 3) * BUFSZ);
    if (ks + 2 < 32) stage(lds + ((ks + 2) % 3) * BUFSZ, ks + 2);
  }

  // store: D layout col=lane&15, row=(lane>>4)*4+reg
#pragma unroll
  for (int mi = 0; mi < 2; ++mi) {
    int rowb = m0 + wr * 32 + mi * 16 + ((lane >> 4) << 2);
#pragma unroll
    for (int ni = 0; ni < 3; ++ni) {
      int col = n0 + ni * 16 + lr;
      float bv = bias[col];
#pragma unroll
      for (int r = 0; r < 4; ++r)
        C[(size_t)(rowb + r) * G3 + col] = acc1[mi][ni][r] + accR[mi][ni][r] * INV_RES + bv;
    }
  }
}

// write one row's 4 consecutive k of both splits into a tiled h array
__device__ __forceinline__ void write_ht(unsigned short (*ht)[2][4][BB][8],
                                         int row, int k0,
                                         u16x4 o1, u16x4 o2) {
  const int ks = k0 >> 5, kk = (k0 >> 3) & 3, e0 = k0 & 7;
  *(u16x4*)&ht[ks][0][kk][row][e0] = o1;
  *(u16x4*)&ht[ks][1][kk][row][e0] = o2;
}

// ---------------- setup kernels ----------------
__global__ __launch_bounds__(NTHR) void k_setup1(
    const float* __restrict__ z, const float* __restrict__ w_zh,
    const float* __restrict__ b_zh, const float* __restrict__ emb,
    const float* __restrict__ w_ih0, const float* __restrict__ b_ih0) {
  __shared__ __align__(16) float As[BM][KT + 4];
  __shared__ __align__(16) float Ws[KT][BN + 4];
  const int bid = blockIdx.x;
  if (bid < 128) {
    int m0 = (bid >> 5) * BM;
    int n0 = (bid & 31) * BN;
    float* Cb;
    int col;
    if (n0 < HH) { Cb = &g_h0[1][0][0]; col = n0; }
    else         { Cb = &g_h1[1][0][0]; col = n0 - HH; }
    gemm_unit(z + m0 * ZZ, ZZ, BM, w_zh + n0 * ZZ, ZZ, b_zh + n0,
              Cb + m0 * HH + col, HH, ZZ, 1, As, Ws);
  } else {
    int n0 = (bid - 128) * BN;
    gemm_unit(emb, EE, VV, w_ih0 + n0 * EE, EE, b_ih0 + n0,
              &g_P0[0][0] + n0, G3, EE, 0, As, Ws);
  }
}

// split + tile the 3 recurrent weight matrices -> g_wt (48-col tiles).
__global__ __launch_bounds__(NTHR) void k_splitw(
    const float* __restrict__ w_ih1, const float* __restrict__ w_hh0,
    const float* __restrict__ w_hh1) {
  unsigned u = blockIdx.x * NTHR + threadIdx.x;   // < 1,179,648
  int row = u % MMN;
  unsigned v = u / MMN;
  int kk = v & 3, ks = (v >> 2) & 31;
  unsigned rem = v >> 7;                           // mat*NBN + bn
  int mat = rem / NBN, bn = rem % NBN;
  const float* src = (mat == 0) ? w_ih1 : (mat == 1) ? w_hh0 : w_hh1;
  const float* p = src + (size_t)(bn * MMN + row) * HH + ks * 32 + kk * 8;
  f4 v0 = *(const f4*)p;
  f4 v1 = *(const f4*)(p + 4);
  u16x8 o1, o2;
#pragma unroll
  for (int c = 0; c < 8; ++c) {
    float x = (c < 4) ? v0[c] : v1[c - 4];
    unsigned short a, b;
    split2(x, a, b);
    o1[c] = a; o2[c] = b;
  }
  *(u16x8*)&g_wt[mat][bn][ks][0][kk][row][0] = o1;
  *(u16x8*)&g_wt[mat][bn][ks][1][kk][row][0] = o2;
}

// split h0init/h1init into tiled g_h0t/g_h1t. One thread per (mat,row,kquad).
__global__ __launch_bounds__(NTHR) void k_splith() {
  unsigned e = blockIdx.x * NTHR + threadIdx.x;   // < 131072
  int mat = e >> 16, r = (e >> 8) & 255, k0 = (e & 255) << 2;
  const float* src = (mat == 0) ? &g_h0[1][0][0] : &g_h1[1][0][0];
  f4 v = *(const f4*)(src + (size_t)r * HH + k0);
  u16x4 o1, o2;
#pragma unroll
  for (int c = 0; c < 4; ++c) {
    unsigned short a, b;
    split2(v[c], a, b);
    o1[c] = a; o2[c] = b;
  }
  write_ht((mat == 0) ? g_h0t : g_h1t, r, k0, o1, o2);
}

// gh0(-1) = h0init @ w_hh0^T + b_hh0 : 2 mt x 64 bn (mat 1 only)
__global__ __launch_bounds__(NTHR, 2) void k_mm_init(const float* __restrict__ b_hh0) {
  __shared__ __align__(16) unsigned short lds[3 * BUFSZ];
  int mt = blockIdx.x >> 6, bn = blockIdx.x & 63;
  mm_tile(&g_h0t[0][0][0][0][0], &g_wt[1][bn][0][0][0][0][0], b_hh0,
          &g_gh0b[0][0], mt * 128, bn * MMN, lds);
}

// gate0 for t=0 (token = SOS = 1)
__global__ __launch_bounds__(NTHR) void k_gate0_init() {
  const int b = blockIdx.x, tid = threadIdx.x, j = tid << 2;
  const float* __restrict__ gi = g_P0[1];
  const float* __restrict__ gh = g_gh0b[b];
  f4 ir = *(const f4*)&gi[j];
  f4 iz = *(const f4*)&gi[j + HH];
  f4 in_ = *(const f4*)&gi[j + 2 * HH];
  f4 hr = *(const f4*)&gh[j];
  f4 hz = *(const f4*)&gh[j + HH];
  f4 hn = *(const f4*)&gh[j + 2 * HH];
  f4 hp = *(const f4*)&g_h0[1][b][j];
  f4 ho;
  u16x4 o1, o2;
#pragma unroll
  for (int c = 0; c < 4; ++c) {
    ho[c] = gru_h(ir[c], hr[c], iz[c], hz[c], in_[c], hn[c], hp[c]);
    unsigned short a, bb2;
    split2(ho[c], a, bb2);
    o1[c] = a; o2[c] = bb2;
  }
  *(f4*)&g_h0[0][b][j] = ho;
  write_ht(g_h0t, b, j, o1, o2);
}

// ---------------- per-step kernels ----------------
// 384 blocks. bid = mt*192 + mat*64 + bn  (partner m-tiles at delta=192 ->
// same XCD -> shared-W L2 hits). mat: 0 gi1, 1 gh0, 2 gh1.
__global__ __launch_bounds__(NTHR, 2) void k_mm(
    const float* __restrict__ b_ih1, const float* __restrict__ b_hh0,
    const float* __restrict__ b_hh1) {
  __shared__ __align__(16) unsigned short lds[3 * BUFSZ];
  const int bid = blockIdx.x;
  const int mt = bid / 192, r = bid % 192;
  const int mat = r >> 6, bn = r & 63;
  const unsigned short* At = (mat == 2) ? &g_h1t[0][0][0][0][0] : &g_h0t[0][0][0][0][0];
  const unsigned short* Wt = &g_wt[mat][bn][0][0][0][0][0];
  const float* bias = (mat == 0) ? b_ih1 : (mat == 1) ? b_hh0 : b_hh1;
  float* C = (mat == 0) ? &g_gi1[0][0] : (mat == 1) ? &g_gh0b[0][0] : &g_gh1b[0][0];
  mm_tile(At, Wt, bias, C, mt * 128, bn * MMN, lds);
}

// GRU1(t) + logits + sample + GRU0(t+1). One batch row per block.
__global__ __launch_bounds__(NTHR) void k_fuse(
    int t, const float* __restrict__ w_out, const float* __restrict__ b_out,
    float* __restrict__ out) {
  __shared__ __align__(16) float s_h[HH];
  __shared__ float s_log[32];
  __shared__ float s_score[32];
  __shared__ int s_tok;
  const int b = blockIdx.x, tid = threadIdx.x, j = tid << 2;
  const int pw = t & 1, pr = pw ^ 1;

  {
    const float* __restrict__ gi = g_gi1[b];
    const float* __restrict__ gh = g_gh1b[b];
    f4 ir = *(const f4*)&gi[j];
    f4 iz = *(const f4*)&gi[j + HH];
    f4 in_ = *(const f4*)&gi[j + 2 * HH];
    f4 hr = *(const f4*)&gh[j];
    f4 hz = *(const f4*)&gh[j + HH];
    f4 hn = *(const f4*)&gh[j + 2 * HH];
    f4 hp = *(const f4*)&g_h1[pr][b][j];
    f4 ho;
    u16x4 o1, o2;
#pragma unroll
    for (int c = 0; c < 4; ++c) {
      ho[c] = gru_h(ir[c], hr[c], iz[c], hz[c], in_[c], hn[c], hp[c]);
      unsigned short a, bb2;
      split2(ho[c], a, bb2);
      o1[c] = a; o2[c] = bb2;
    }
    *(f4*)&g_h1[pw][b][j] = ho;
    *(f4*)&s_h[j] = ho;
    write_ht(g_h1t, b, j, o1, o2);
  }
  __syncthreads();

  {
    const int v = tid >> 3, ks = tid & 7;
    float part = 0.f;
    if (v < VV) {
      const float* __restrict__ wrow = w_out + v * HH + ks * 128;
      const float* __restrict__ hh = s_h + ks * 128;
#pragma unroll 8
      for (int i = 0; i < 128; i += 4) {
        f4 wv = *(const f4*)&wrow[i];
        f4 hv = *(const f4*)&hh[i];
        part += hv[0] * wv[0] + hv[1] * wv[1] + hv[2] * wv[2] + hv[3] * wv[3];
      }
    }
    part += __shfl_xor(part, 1);
    part += __shfl_xor(part, 2);
    part += __shfl_xor(part, 4);
    if (v < VV && ks == 0) s_log[v] = part;
  }
  __syncthreads();

  if (tid < VV) {
    float logit = s_log[tid] + b_out[tid];
    out[(size_t)b * (TT * VV) + (size_t)t * VV + tid] = logit;
    uint2 kt = tf2x32(0u, 42u, 0u, (unsigned)t);
    uint2 rr = tf2x32(kt.x, kt.y, 0u, (unsigned)(b * VV + tid));
    unsigned bits = rr.x ^ rr.y;
    float uf = __uint_as_float((bits >> 9) | 0x3f800000u) - 1.0f;
    if (uf <= 0.0f) uf = 1.17549435e-38f;  // finfo(f32).tiny
    s_score[tid] = logit - logf(-logf(uf));
  }
  __syncthreads();
  if (tid == 0) {
    float best = s_score[0];
    int bv = 0;
    for (int vv = 1; vv < VV; ++vv) {
      float s = s_score[vv];
      if (s > best) { best = s; bv = vv; }  // strict >: first max
    }
    s_tok = bv;
    out[TOKBASE + (size_t)b * TT + t] = (float)bv;
  }
  __syncthreads();

  {
    const int tok = s_tok;
    const float* __restrict__ gi = g_P0[tok];
    const float* __restrict__ gh = g_gh0b[b];
    f4 ir = *(const f4*)&gi[j];
    f4 iz = *(const f4*)&gi[j + HH];
    f4 in_ = *(const f4*)&gi[j + 2 * HH];
    f4 hr = *(const f4*)&gh[j];
    f4 hz = *(const f4*)&gh[j + HH];
    f4 hn = *(const f4*)&gh[j + 2 * HH];
    f4 hp = *(const f4*)&g_h0[pw][b][j];
    f4 ho;
    u16x4 o1, o2;
#pragma unroll
    for (int c = 0; c < 4; ++c) {
      ho[c] = gru_h(ir[c], hr[c], iz[c], hz[c], in_[c], hn[c], hp[c]);
      unsigned short a, bb2;
      split2(ho[c], a, bb2);
      o1[c] = a; o2[c] = bb2;
    }
    *(f4*)&g_h0[pr][b][j] = ho;
    write_ht(g_h0t, b, j, o1, o2);
  }
}

extern "C" void kernel_launch(void* const* d_in, const int* in_sizes, int n_in,
                              void* d_out, int out_size, void* d_ws, size_t ws_size,
                              hipStream_t stream) {
  (void)in_sizes; (void)n_in; (void)d_ws; (void)ws_size; (void)out_size;
  const float* z     = (const float*)d_in[0];
  const float* emb   = (const float*)d_in[1];
  const float* w_zh  = (const float*)d_in[2];
  const float* b_zh  = (const float*)d_in[3];
  const float* w_ih0 = (const float*)d_in[4];
  const float* w_hh0 = (const float*)d_in[5];
  const float* b_ih0 = (const float*)d_in[6];
  const float* b_hh0 = (const float*)d_in[7];
  const float* w_ih1 = (const float*)d_in[8];
  const float* w_hh1 = (const float*)d_in[9];
  const float* b_ih1 = (const float*)d_in[10];
  const float* b_hh1 = (const float*)d_in[11];
  const float* w_out = (const float*)d_in[12];
  const float* b_out = (const float*)d_in[13];
  float* out = (float*)d_out;

  k_setup1<<<dim3(176), dim3(NTHR), 0, stream>>>(z, w_zh, b_zh, emb, w_ih0, b_ih0);
  k_splitw<<<dim3(4608), dim3(NTHR), 0, stream>>>(w_ih1, w_hh0, w_hh1);
  k_splith<<<dim3(512), dim3(NTHR), 0, stream>>>();
  k_mm_init<<<dim3(128), dim3(NTHR), 0, stream>>>(b_hh0);
  k_gate0_init<<<dim3(BB), dim3(NTHR), 0, stream>>>();

  for (int t = 0; t < TT; ++t) {
    k_mm<<<dim3(384), dim3(NTHR), 0, stream>>>(b_ih1, b_hh0, b_hh1);
    k_fuse<<<dim3(BB), dim3(NTHR), 0, stream>>>(t, w_out, b_out, out);
  }
}